// Round 1
// baseline (19465.176 us; speedup 1.0000x reference)
//
#include <hip/hip_runtime.h>
#include <math.h>

#define B_ 8
#define S_ 2048
#define E_ 1024
#define H_ 1024
#define M_ 16384   // B_*S_

// ---------------- block-wide reduction of two floats (256 threads = 4 waves) ----------------
__device__ __forceinline__ void block_reduce2(float &a, float &b) {
#pragma unroll
  for (int off = 32; off > 0; off >>= 1) {
    a += __shfl_down(a, off);
    b += __shfl_down(b, off);
  }
  __shared__ float sa[4], sb[4];
  const int w = threadIdx.x >> 6;
  __syncthreads();                 // protects reuse across back-to-back calls
  if ((threadIdx.x & 63) == 0) { sa[w] = a; sb[w] = b; }
  __syncthreads();
  a = sa[0] + sa[1] + sa[2] + sa[3];
  b = sb[0] + sb[1] + sb[2] + sb[3];
}

// ---------------- LayerNorm(x) -> x_norm, plus delta = softplus(x_norm . delta_w + delta_b) ----------------
__global__ __launch_bounds__(256) void ln_delta_kernel(
    const float* __restrict__ x, const float* __restrict__ g, const float* __restrict__ bt,
    const float* __restrict__ dw, const float* __restrict__ db,
    float* __restrict__ xn, float* __restrict__ delta)
{
  const int row = blockIdx.x;
  const int t = threadIdx.x;
  const float4 v = ((const float4*)(x + (size_t)row * E_))[t];
  float s1 = v.x + v.y + v.z + v.w;
  float s2 = v.x*v.x + v.y*v.y + v.z*v.z + v.w*v.w;
  block_reduce2(s1, s2);
  const float mean = s1 * (1.f / E_);
  const float var  = s2 * (1.f / E_) - mean * mean;
  const float rstd = rsqrtf(var + 1e-5f);
  const float4 g4 = ((const float4*)g)[t];
  const float4 b4 = ((const float4*)bt)[t];
  float4 o;
  o.x = (v.x - mean) * rstd * g4.x + b4.x;
  o.y = (v.y - mean) * rstd * g4.y + b4.y;
  o.z = (v.z - mean) * rstd * g4.z + b4.z;
  o.w = (v.w - mean) * rstd * g4.w + b4.w;
  ((float4*)(xn + (size_t)row * E_))[t] = o;
  const float4 d4 = ((const float4*)dw)[t];
  float dd = o.x*d4.x + o.y*d4.y + o.z*d4.z + o.w*d4.w;
  float dummy = 0.f;
  block_reduce2(dd, dummy);
  if (t == 0) {
    const float z = dd + db[0];
    delta[row] = (z > 20.f) ? z : log1pf(__expf(z));
  }
}

// ---------------- per-row mean/rstd of reservoir states (for fused ro-layernorm) ----------------
__global__ __launch_bounds__(256) void rowstats_kernel(
    const float* __restrict__ res, float2* __restrict__ st)
{
  const int row = blockIdx.x;
  const int t = threadIdx.x;
  const float4 v = ((const float4*)(res + (size_t)row * H_))[t];
  float s1 = v.x + v.y + v.z + v.w;
  float s2 = v.x*v.x + v.y*v.y + v.z*v.z + v.w*v.w;
  block_reduce2(s1, s2);
  if (t == 0) {
    const float m = s1 * (1.f / H_);
    const float var = s2 * (1.f / H_) - m * m;
    st[row] = make_float2(m, rsqrtf(var + 1e-5f));
  }
}

// ---------------- generic fp32 GEMM: C[M,N] = act(A[M,K] @ W[N,K]^T + bias), N=K=1024 ----------------
// ACT: 0 none, 1 sigmoid, 2 gelu(exact)
template<int ACT>
__global__ __launch_bounds__(256) void gemm_nt_kernel(
    const float* __restrict__ A, const float* __restrict__ W,
    const float* __restrict__ bias, float* __restrict__ C)
{
  __shared__ float As[16][132];
  __shared__ float Ws[16][68];
  const int tid = threadIdx.x;
  const int bn = blockIdx.x & 15;
  const int bm = blockIdx.x >> 4;
  const int tx = tid & 15;
  const int ty = tid >> 4;
  const int sr = tid >> 2;   // staging row / n
  const int sk = tid & 3;    // staging k-f4 chunk
  float acc[8][4];
#pragma unroll
  for (int i = 0; i < 8; ++i)
#pragma unroll
    for (int j = 0; j < 4; ++j) acc[i][j] = 0.f;

  for (int k0 = 0; k0 < 1024; k0 += 16) {
#pragma unroll
    for (int p = 0; p < 2; ++p) {
      const int row = sr + p * 64;
      const float4 a4 = *(const float4*)(A + (size_t)(bm * 128 + row) * 1024 + k0 + sk * 4);
      As[sk*4+0][row] = a4.x; As[sk*4+1][row] = a4.y;
      As[sk*4+2][row] = a4.z; As[sk*4+3][row] = a4.w;
    }
    {
      const float4 w4 = *(const float4*)(W + (size_t)(bn * 64 + sr) * 1024 + k0 + sk * 4);
      Ws[sk*4+0][sr] = w4.x; Ws[sk*4+1][sr] = w4.y;
      Ws[sk*4+2][sr] = w4.z; Ws[sk*4+3][sr] = w4.w;
    }
    __syncthreads();
#pragma unroll
    for (int kk = 0; kk < 16; ++kk) {
      const float4 a0 = *(const float4*)&As[kk][ty * 4];
      const float4 a1 = *(const float4*)&As[kk][64 + ty * 4];
      const float4 b0 = *(const float4*)&Ws[kk][tx * 4];
      const float ar[8] = {a0.x,a0.y,a0.z,a0.w,a1.x,a1.y,a1.z,a1.w};
      const float bc[4] = {b0.x,b0.y,b0.z,b0.w};
#pragma unroll
      for (int i = 0; i < 8; ++i)
#pragma unroll
        for (int j = 0; j < 4; ++j)
          acc[i][j] += ar[i] * bc[j];
    }
    __syncthreads();
  }
  float bv[4] = {0.f, 0.f, 0.f, 0.f};
  if (bias) {
    const float4 b4 = *(const float4*)(bias + bn * 64 + tx * 4);
    bv[0] = b4.x; bv[1] = b4.y; bv[2] = b4.z; bv[3] = b4.w;
  }
#pragma unroll
  for (int i = 0; i < 8; ++i) {
    const int row = bm * 128 + ((i < 4) ? (ty * 4 + i) : (64 + ty * 4 + i - 4));
    float4 o;
    float* po = &o.x;
#pragma unroll
    for (int j = 0; j < 4; ++j) {
      float v = acc[i][j] + bv[j];
      if (ACT == 1) v = 1.f / (1.f + __expf(-v));
      if (ACT == 2) v = 0.5f * v * (1.f + erff(v * 0.70710678118654752f));
      po[j] = v;
    }
    *(float4*)(C + (size_t)row * 1024 + bn * 64 + tx * 4) = o;
  }
}

// ---------------- readout GEMM: fused ro-layernorm on A, gelu, ssm reconstruction, gate blend ----------------
__global__ __launch_bounds__(256) void gemm_readout_kernel(
    const float* __restrict__ A,      // reservoir states [M,1024]
    const float* __restrict__ W,      // ro_w [1024,1024]
    const float* __restrict__ bias,   // ro_bias
    const float2* __restrict__ lnst,  // per-row mean/rstd
    const float* __restrict__ lng, const float* __restrict__ lnb,
    const float* __restrict__ Avec,   // A[h]
    const float* __restrict__ cumd,   // within-chunk cumulative delta [M]
    const float* __restrict__ chH,    // per-chunk initial ssm state [B,16,1024]
    const float* __restrict__ gate,   // [M,1024]
    float* __restrict__ C)            // d_out: in = ssm local states, out = final
{
  __shared__ float As[16][132];
  __shared__ float Ws[16][68];
  const int tid = threadIdx.x;
  const int bn = blockIdx.x & 15;
  const int bm = blockIdx.x >> 4;
  const int tx = tid & 15;
  const int ty = tid >> 4;
  const int sr = tid >> 2;
  const int sk = tid & 3;
  float acc[8][4];
#pragma unroll
  for (int i = 0; i < 8; ++i)
#pragma unroll
    for (int j = 0; j < 4; ++j) acc[i][j] = 0.f;

  for (int k0 = 0; k0 < 1024; k0 += 16) {
    const float4 g4 = *(const float4*)(lng + k0 + sk * 4);
    const float4 b4 = *(const float4*)(lnb + k0 + sk * 4);
#pragma unroll
    for (int p = 0; p < 2; ++p) {
      const int row = sr + p * 64;
      const int gr = bm * 128 + row;
      float4 a4 = *(const float4*)(A + (size_t)gr * 1024 + k0 + sk * 4);
      const float2 st = lnst[gr];
      a4.x = (a4.x - st.x) * st.y * g4.x + b4.x;
      a4.y = (a4.y - st.x) * st.y * g4.y + b4.y;
      a4.z = (a4.z - st.x) * st.y * g4.z + b4.z;
      a4.w = (a4.w - st.x) * st.y * g4.w + b4.w;
      As[sk*4+0][row] = a4.x; As[sk*4+1][row] = a4.y;
      As[sk*4+2][row] = a4.z; As[sk*4+3][row] = a4.w;
    }
    {
      const float4 w4 = *(const float4*)(W + (size_t)(bn * 64 + sr) * 1024 + k0 + sk * 4);
      Ws[sk*4+0][sr] = w4.x; Ws[sk*4+1][sr] = w4.y;
      Ws[sk*4+2][sr] = w4.z; Ws[sk*4+3][sr] = w4.w;
    }
    __syncthreads();
#pragma unroll
    for (int kk = 0; kk < 16; ++kk) {
      const float4 a0 = *(const float4*)&As[kk][ty * 4];
      const float4 a1 = *(const float4*)&As[kk][64 + ty * 4];
      const float4 b0 = *(const float4*)&Ws[kk][tx * 4];
      const float ar[8] = {a0.x,a0.y,a0.z,a0.w,a1.x,a1.y,a1.z,a1.w};
      const float bc[4] = {b0.x,b0.y,b0.z,b0.w};
#pragma unroll
      for (int i = 0; i < 8; ++i)
#pragma unroll
        for (int j = 0; j < 4; ++j)
          acc[i][j] += ar[i] * bc[j];
    }
    __syncthreads();
  }
  const int col0 = bn * 64 + tx * 4;
  const float4 Ah4 = *(const float4*)(Avec + col0);
  const float4 bs4 = *(const float4*)(bias + col0);
  const float Ah[4] = {Ah4.x, Ah4.y, Ah4.z, Ah4.w};
  const float bv[4] = {bs4.x, bs4.y, bs4.z, bs4.w};
#pragma unroll
  for (int i = 0; i < 8; ++i) {
    const int gr = bm * 128 + ((i < 4) ? (ty * 4 + i) : (64 + ty * 4 + i - 4));
    const int b = gr >> 11;          // gr = b*2048 + s
    const int s = gr & 2047;
    const int c = s >> 7;            // 128-step chunk
    const float cd = cumd[gr];
    const size_t off = (size_t)gr * 1024 + col0;
    const float4 hin4 = *(const float4*)(chH + (size_t)((b * 16 + c) << 10) + col0);
    const float4 lcl4 = *(const float4*)(C + off);
    const float4 gt4  = *(const float4*)(gate + off);
    const float hin[4] = {hin4.x, hin4.y, hin4.z, hin4.w};
    const float lcl[4] = {lcl4.x, lcl4.y, lcl4.z, lcl4.w};
    const float gt[4]  = {gt4.x, gt4.y, gt4.z, gt4.w};
    float4 o;
    float* po = &o.x;
#pragma unroll
    for (int j = 0; j < 4; ++j) {
      float v = acc[i][j] + bv[j];
      v = 0.5f * v * (1.f + erff(v * 0.70710678118654752f));   // exact gelu
      const float p = __expf(Ah[j] * cd);                      // prod of A_bar over chunk prefix
      const float sst = lcl[j] + p * hin[j];                   // true ssm state
      po[j] = v * gt[j] + sst * (1.f - gt[j]);
    }
    *(float4*)(C + off) = o;
  }
}

// ---------------- reservoir scan: persistent 64-WG kernel with atomic grid barrier ----------------
__device__ __forceinline__ void grid_barrier(unsigned* cnt, unsigned target) {
  __syncthreads();                     // drains this WG's vmem (compiler emits vmcnt(0) before s_barrier)
  if (threadIdx.x == 0) {
    __threadfence();                   // agent-scope release of this WG's stores
    __hip_atomic_fetch_add(cnt, 1u, __ATOMIC_RELEASE, __HIP_MEMORY_SCOPE_AGENT);
    while (__hip_atomic_load(cnt, __ATOMIC_ACQUIRE, __HIP_MEMORY_SCOPE_AGENT) < target) {
      __builtin_amdgcn_s_sleep(2);
    }
    __threadfence();                   // acquire-side cache invalidate (CU/XCD-wide)
  }
  __syncthreads();
}

__global__ __launch_bounds__(256, 1) void reservoir_scan_kernel(
    float* __restrict__ xin_res,       // [8][2048][1024]: in xin, out res states (in-place)
    const float* __restrict__ Wres,    // [1024][1024]
    float* __restrict__ hbuf,          // [2][8][1024], zeroed before launch
    unsigned* __restrict__ barcnt)     // zeroed before launch
{
  const int tid = threadIdx.x;
  const int wg  = blockIdx.x;          // 0..63
  const int g   = tid >> 6;            // wave 0..3
  const int ks  = tid & 63;
  const int j0  = wg * 16;
  __shared__ float hs[8192];           // [8][1024]; aliased as reduction scratch after compute
  float4* hs4 = (float4*)hs;

  // W_res slice in registers: rows j0+g*4+r, f4 chunks ks+64*i
  float4 wreg[4][4];
#pragma unroll
  for (int r = 0; r < 4; ++r) {
    const float4* wrow = (const float4*)(Wres + (size_t)(j0 + g * 4 + r) * H_);
#pragma unroll
    for (int i = 0; i < 4; ++i) wreg[r][i] = wrow[ks + 64 * i];
  }

  const int o    = ks & 31;
  const int ob   = o & 7;              // batch
  const int orow = o >> 3;             // 0..3
  const int oj   = j0 + g * 4 + orow;  // global hidden index

  for (int s = 0; s < S_; ++s) {
    // stage h_prev into LDS
    const float4* hp = (const float4*)(hbuf + (size_t)(s & 1) * 8192);
#pragma unroll
    for (int i = 0; i < 8; ++i) hs4[tid + 256 * i] = hp[tid + 256 * i];
    __syncthreads();

    float acc[4][8];
#pragma unroll
    for (int r = 0; r < 4; ++r)
#pragma unroll
      for (int b = 0; b < 8; ++b) acc[r][b] = 0.f;
#pragma unroll
    for (int i = 0; i < 4; ++i) {
      float4 h4[8];
#pragma unroll
      for (int b = 0; b < 8; ++b) h4[b] = hs4[b * 256 + ks + 64 * i];
#pragma unroll
      for (int r = 0; r < 4; ++r) {
        const float4 w = wreg[r][i];
#pragma unroll
        for (int b = 0; b < 8; ++b) {
          const float4 h = h4[b];
          acc[r][b] += w.x * h.x + w.y * h.y + w.z * h.z + w.w * h.w;
        }
      }
    }
    const float hprev = hs[ob * 1024 + oj];                       // before scratch overwrites
    const float u = xin_res[((size_t)ob * S_ + s) * H_ + oj];     // prefetch, overlaps reduction
    __syncthreads();                                              // all LDS reads done

    // swizzled per-wave reduction scratch (aliases hs)
    float* red = hs + (g << 11);
#pragma unroll
    for (int r = 0; r < 4; ++r)
#pragma unroll
      for (int b = 0; b < 8; ++b) {
        const int v = r * 8 + b;
        red[ks * 32 + ((v + ks) & 31)] = acc[r][b];
      }
    __syncthreads();
    float psum = 0.f;
    const int half = ks >> 5;
#pragma unroll
    for (int t = 0; t < 32; ++t) {
      const int l = half * 32 + t;
      psum += red[l * 32 + ((o + l) & 31)];
    }
    psum += __shfl_xor(psum, 32);

    const float hn = tanhf(u + psum);
    const float hv = 0.95f * hn + 0.05f * hprev;
    if (ks < 32) {
      xin_res[((size_t)ob * S_ + s) * H_ + oj] = hv;
      hbuf[(size_t)((s + 1) & 1) * 8192 + ob * 1024 + oj] = hv;
    }
    grid_barrier(barcnt, 64u * (unsigned)(s + 1));
  }
}

// ---------------- SSM chunked scan ----------------
// within-chunk cumulative delta (tiny)
__global__ __launch_bounds__(128) void cumd_kernel(
    const float* __restrict__ delta, float* __restrict__ cumd)
{
  const int t = threadIdx.x;          // 128 = 8 batches * 16 chunks
  const int b = t >> 4, c = t & 15;
  const int base = b * S_ + c * 128;
  float acc = 0.f;
  for (int i = 0; i < 128; ++i) { acc += delta[base + i]; cumd[base + i] = acc; }
}

// phase A: per-chunk local scan, in-place Bx -> local states; store chunk products
__global__ __launch_bounds__(256) void ssm_partial_kernel(
    const float* __restrict__ delta, const float* __restrict__ Avec,
    float* __restrict__ bx, float* __restrict__ P)
{
  const int idx = blockIdx.x * 256 + threadIdx.x;
  const int h = idx & 1023;
  const int c = (idx >> 10) & 15;
  const int b = idx >> 14;
  const float Ah = Avec[h];
  const float inv = 1.f / (Ah + 1e-8f);
  const float* dp = delta + b * S_ + c * 128;
  float* xp = bx + ((size_t)(b * S_ + c * 128)) * H_ + h;
  float p = 1.f, hl = 0.f;
  for (int t = 0; t < 128; ++t) {
    const float a = __expf(Ah * dp[t]);
    const float bb = xp[(size_t)t * H_] * (1.f - a) * inv;
    hl = a * hl + bb;
    p *= a;
    xp[(size_t)t * H_] = hl;
  }
  P[(b * 16 + c) * 1024 + h] = p;
}

// phase B: sequential combine over 16 chunks -> per-chunk initial states
__global__ __launch_bounds__(256) void ssm_combine_kernel(
    const float* __restrict__ P, const float* __restrict__ local, float* __restrict__ Hin)
{
  const int idx = blockIdx.x * 256 + threadIdx.x;  // 8192
  const int h = idx & 1023;
  const int b = idx >> 10;
  float hh = 0.f;
#pragma unroll
  for (int c = 0; c < 16; ++c) {
    const int o = (b * 16 + c) * 1024 + h;
    Hin[o] = hh;
    hh = P[o] * hh + local[((size_t)(b * S_ + c * 128 + 127)) * H_ + h];
  }
}

// ---------------- host launch ----------------
extern "C" void kernel_launch(void* const* d_in, const int* in_sizes, int n_in,
                              void* d_out, int out_size, void* d_ws, size_t ws_size,
                              hipStream_t stream) {
  (void)in_sizes; (void)n_in; (void)out_size; (void)ws_size;
  const float* x      = (const float*)d_in[0];
  const float* W_in   = (const float*)d_in[1];
  const float* W_res  = (const float*)d_in[2];
  const float* norm_g = (const float*)d_in[3];
  const float* norm_b = (const float*)d_in[4];
  const float* dw     = (const float*)d_in[5];
  const float* db     = (const float*)d_in[6];
  const float* Avec   = (const float*)d_in[7];
  const float* B_w    = (const float*)d_in[8];
  const float* ro_g   = (const float*)d_in[9];
  const float* ro_b   = (const float*)d_in[10];
  const float* ro_w   = (const float*)d_in[11];
  const float* ro_bias= (const float*)d_in[12];
  const float* gate_w = (const float*)d_in[13];
  const float* gate_b = (const float*)d_in[14];
  float* out = (float*)d_out;
  float* ws  = (float*)d_ws;

  float*    buf0   = ws;                    // x_norm, later gate
  float*    buf1   = ws + 16777216;         // xin -> reservoir states (in-place)
  float*    delta  = ws + 33554432;         // [M]
  float*    cumd   = ws + 33570816;         // [M]
  float*    hbuf   = ws + 33587200;         // [2][8][1024]
  unsigned* barcnt = (unsigned*)(ws + 33603584);
  float2*   stats  = (float2*)(ws + 33603712);
  float*    chP    = ws + 33636480;         // [B,16,1024]
  float*    chH    = ws + 33767552;         // [B,16,1024]

  // 1. layernorm + delta
  ln_delta_kernel<<<M_, 256, 0, stream>>>(x, norm_g, norm_b, dw, db, buf0, delta);
  // 2. xin = x_norm @ W_in^T   -> buf1
  gemm_nt_kernel<0><<<2048, 256, 0, stream>>>(buf0, W_in, nullptr, buf1);
  // 3. Bx = x_norm @ B_w^T     -> d_out (scratch)
  gemm_nt_kernel<0><<<2048, 256, 0, stream>>>(buf0, B_w, nullptr, out);
  // 4. gate = sigmoid(x @ gate_w^T + gate_b) -> buf0 (x_norm dead)
  gemm_nt_kernel<1><<<2048, 256, 0, stream>>>(x, gate_w, gate_b, buf0);
  // 5. ssm chunked scan pieces (independent of reservoir)
  cumd_kernel<<<1, 128, 0, stream>>>(delta, cumd);
  ssm_partial_kernel<<<512, 256, 0, stream>>>(delta, Avec, out, chP);
  ssm_combine_kernel<<<32, 256, 0, stream>>>(chP, out, chH);
  // 6. reservoir scan (zero h0 + barrier counter first)
  hipMemsetAsync(hbuf, 0, (16384 + 128) * sizeof(float), stream);
  reservoir_scan_kernel<<<64, 256, 0, stream>>>(buf1, W_res, hbuf, barcnt);
  // 7. ro-layernorm stats
  rowstats_kernel<<<M_, 256, 0, stream>>>(buf1, stats);
  // 8. readout GEMM + gelu + ssm reconstruction + gate blend -> d_out
  gemm_readout_kernel<<<2048, 256, 0, stream>>>(buf1, ro_w, ro_bias, stats, ro_g, ro_b,
                                                Avec, cumd, chH, buf0, out);
}

// Round 3
// 13092.943 us; speedup vs baseline: 1.4867x; 1.4867x over previous
//
#include <hip/hip_runtime.h>
#include <math.h>

#define B_ 8
#define S_ 2048
#define E_ 1024
#define H_ 1024
#define M_ 16384   // B_*S_

typedef __attribute__((ext_vector_type(8))) short short8;    // 8 bf16 = 4 VGPRs
typedef __attribute__((ext_vector_type(4))) float floatx4;

// ---------------- block-wide reduction of two floats (256 threads = 4 waves) ----------------
__device__ __forceinline__ void block_reduce2(float &a, float &b) {
#pragma unroll
  for (int off = 32; off > 0; off >>= 1) {
    a += __shfl_down(a, off);
    b += __shfl_down(b, off);
  }
  __shared__ float sa[4], sb[4];
  const int w = threadIdx.x >> 6;
  __syncthreads();                 // protects reuse across back-to-back calls
  if ((threadIdx.x & 63) == 0) { sa[w] = a; sb[w] = b; }
  __syncthreads();
  a = sa[0] + sa[1] + sa[2] + sa[3];
  b = sb[0] + sb[1] + sb[2] + sb[3];
}

// ---------------- LayerNorm(x) -> x_norm, plus delta = softplus(x_norm . delta_w + delta_b) ----------------
__global__ __launch_bounds__(256) void ln_delta_kernel(
    const float* __restrict__ x, const float* __restrict__ g, const float* __restrict__ bt,
    const float* __restrict__ dw, const float* __restrict__ db,
    float* __restrict__ xn, float* __restrict__ delta)
{
  const int row = blockIdx.x;
  const int t = threadIdx.x;
  const float4 v = ((const float4*)(x + (size_t)row * E_))[t];
  float s1 = v.x + v.y + v.z + v.w;
  float s2 = v.x*v.x + v.y*v.y + v.z*v.z + v.w*v.w;
  block_reduce2(s1, s2);
  const float mean = s1 * (1.f / E_);
  const float var  = s2 * (1.f / E_) - mean * mean;
  const float rstd = rsqrtf(var + 1e-5f);
  const float4 g4 = ((const float4*)g)[t];
  const float4 b4 = ((const float4*)bt)[t];
  float4 o;
  o.x = (v.x - mean) * rstd * g4.x + b4.x;
  o.y = (v.y - mean) * rstd * g4.y + b4.y;
  o.z = (v.z - mean) * rstd * g4.z + b4.z;
  o.w = (v.w - mean) * rstd * g4.w + b4.w;
  ((float4*)(xn + (size_t)row * E_))[t] = o;
  const float4 d4 = ((const float4*)dw)[t];
  float dd = o.x*d4.x + o.y*d4.y + o.z*d4.z + o.w*d4.w;
  float dummy = 0.f;
  block_reduce2(dd, dummy);
  if (t == 0) {
    const float z = dd + db[0];
    delta[row] = (z > 20.f) ? z : log1pf(__expf(z));
  }
}

// ---------------- per-row mean/rstd of reservoir states (for fused ro-layernorm) ----------------
__global__ __launch_bounds__(256) void rowstats_kernel(
    const float* __restrict__ res, float2* __restrict__ st)
{
  const int row = blockIdx.x;
  const int t = threadIdx.x;
  const float4 v = ((const float4*)(res + (size_t)row * H_))[t];
  float s1 = v.x + v.y + v.z + v.w;
  float s2 = v.x*v.x + v.y*v.y + v.z*v.z + v.w*v.w;
  block_reduce2(s1, s2);
  if (t == 0) {
    const float m = s1 * (1.f / H_);
    const float var = s2 * (1.f / H_) - m * m;
    st[row] = make_float2(m, rsqrtf(var + 1e-5f));
  }
}

// ---------------- bf16 MFMA GEMM: C[M,N] = act(A[M,1024] @ W[N,1024]^T + bias) ----------------
// 128x128 tile, 4 waves in 2x2, each wave 64x64 = 4x4 MFMA 16x16x32 tiles.
// fp32 inputs converted to bf16 (round-half-up via +0x8000 then v_perm) during staging.
// LDS row stride 40 elems (80 B): ds_read_b128 lands 2 lanes/bank (free, m136).
// ACT: 0 none, 1 sigmoid
__device__ __forceinline__ unsigned pack_bf16(float lo, float hi) {
  return __builtin_amdgcn_perm(__float_as_uint(hi) + 0x8000u,
                               __float_as_uint(lo) + 0x8000u, 0x07060302u);
}

template<int ACT>
__global__ __launch_bounds__(256) void gemm_bf16_nt(
    const float* __restrict__ A, const float* __restrict__ W,
    const float* __restrict__ bias, float* __restrict__ C)
{
  __shared__ __align__(16) unsigned short As[128 * 40];
  __shared__ __align__(16) unsigned short Ws[128 * 40];
  const int tid  = threadIdx.x;
  const int bn   = blockIdx.x & 7;
  const int bm   = blockIdx.x >> 3;
  const int wave = tid >> 6, lane = tid & 63;
  const int wm = (wave >> 1) * 64, wn = (wave & 1) * 64;
  const int fm = lane & 15, quad = lane >> 4;

  floatx4 acc[4][4];
#pragma unroll
  for (int i = 0; i < 4; ++i)
#pragma unroll
    for (int j = 0; j < 4; ++j) acc[i][j] = (floatx4){0.f, 0.f, 0.f, 0.f};

  const float* Abase = A + (size_t)bm * 128 * 1024;
  const float* Wbase = W + (size_t)bn * 128 * 1024;

  for (int k0 = 0; k0 < 1024; k0 += 32) {
    float4 a4[4], w4[4];
#pragma unroll
    for (int i = 0; i < 4; ++i) {
      const int q = tid + 256 * i;
      const int row = q >> 3, ch = q & 7;
      a4[i] = *(const float4*)(Abase + (size_t)row * 1024 + k0 + ch * 4);
      w4[i] = *(const float4*)(Wbase + (size_t)row * 1024 + k0 + ch * 4);
    }
#pragma unroll
    for (int i = 0; i < 4; ++i) {
      const int q = tid + 256 * i;
      const int row = q >> 3, ch = q & 7;
      uint2 pa, pw;
      pa.x = pack_bf16(a4[i].x, a4[i].y); pa.y = pack_bf16(a4[i].z, a4[i].w);
      pw.x = pack_bf16(w4[i].x, w4[i].y); pw.y = pack_bf16(w4[i].z, w4[i].w);
      *(uint2*)(&As[row * 40 + ch * 4]) = pa;
      *(uint2*)(&Ws[row * 40 + ch * 4]) = pw;
    }
    __syncthreads();
    short8 af[4], wf[4];
#pragma unroll
    for (int i = 0; i < 4; ++i) {
      af[i] = *(const short8*)(&As[(wm + i * 16 + fm) * 40 + quad * 8]);
      wf[i] = *(const short8*)(&Ws[(wn + i * 16 + fm) * 40 + quad * 8]);
    }
#pragma unroll
    for (int i = 0; i < 4; ++i)
#pragma unroll
      for (int j = 0; j < 4; ++j)
        acc[i][j] = __builtin_amdgcn_mfma_f32_16x16x32_bf16(af[i], wf[j], acc[i][j], 0, 0, 0);
    __syncthreads();
  }

  // epilogue: C/D layout col=lane&15, row=quad*4+reg (m89/m91)
#pragma unroll
  for (int i = 0; i < 4; ++i) {
    const int grow0 = bm * 128 + wm + i * 16 + quad * 4;
#pragma unroll
    for (int j = 0; j < 4; ++j) {
      const int gcol = bn * 128 + wn + j * 16 + fm;
      const float bb = (ACT == 1) ? bias[gcol] : 0.f;
#pragma unroll
      for (int r = 0; r < 4; ++r) {
        float v = acc[i][j][r] + bb;
        if (ACT == 1) v = 1.f / (1.f + __expf(-v));
        C[(size_t)(grow0 + r) * 1024 + gcol] = v;
      }
    }
  }
}

// ---------------- readout GEMM: fused ro-layernorm on A, gelu, ssm reconstruction, gate blend ----------------
__global__ __launch_bounds__(256) void gemm_readout_kernel(
    const float* __restrict__ A,      // reservoir states [M,1024]
    const float* __restrict__ W,      // ro_w [1024,1024]
    const float* __restrict__ bias,   // ro_bias
    const float2* __restrict__ lnst,  // per-row mean/rstd
    const float* __restrict__ lng, const float* __restrict__ lnb,
    const float* __restrict__ Avec,   // A[h]
    const float* __restrict__ cumd,   // within-chunk cumulative delta [M]
    const float* __restrict__ chH,    // per-chunk initial ssm state [B,16,1024]
    const float* __restrict__ gate,   // [M,1024]
    float* __restrict__ C)            // d_out: in = ssm local states, out = final
{
  __shared__ float As[16][132];
  __shared__ float Wt[16][68];
  const int tid = threadIdx.x;
  const int bn = blockIdx.x & 15;
  const int bm = blockIdx.x >> 4;
  const int tx = tid & 15;
  const int ty = tid >> 4;
  const int sr = tid >> 2;
  const int sk = tid & 3;
  float acc[8][4];
#pragma unroll
  for (int i = 0; i < 8; ++i)
#pragma unroll
    for (int j = 0; j < 4; ++j) acc[i][j] = 0.f;

  for (int k0 = 0; k0 < 1024; k0 += 16) {
    const float4 g4 = *(const float4*)(lng + k0 + sk * 4);
    const float4 b4 = *(const float4*)(lnb + k0 + sk * 4);
#pragma unroll
    for (int p = 0; p < 2; ++p) {
      const int row = sr + p * 64;
      const int gr = bm * 128 + row;
      float4 a4 = *(const float4*)(A + (size_t)gr * 1024 + k0 + sk * 4);
      const float2 st = lnst[gr];
      a4.x = (a4.x - st.x) * st.y * g4.x + b4.x;
      a4.y = (a4.y - st.x) * st.y * g4.y + b4.y;
      a4.z = (a4.z - st.x) * st.y * g4.z + b4.z;
      a4.w = (a4.w - st.x) * st.y * g4.w + b4.w;
      As[sk*4+0][row] = a4.x; As[sk*4+1][row] = a4.y;
      As[sk*4+2][row] = a4.z; As[sk*4+3][row] = a4.w;
    }
    {
      const float4 w4 = *(const float4*)(W + (size_t)(bn * 64 + sr) * 1024 + k0 + sk * 4);
      Wt[sk*4+0][sr] = w4.x; Wt[sk*4+1][sr] = w4.y;
      Wt[sk*4+2][sr] = w4.z; Wt[sk*4+3][sr] = w4.w;
    }
    __syncthreads();
#pragma unroll
    for (int kk = 0; kk < 16; ++kk) {
      const float4 a0 = *(const float4*)&As[kk][ty * 4];
      const float4 a1 = *(const float4*)&As[kk][64 + ty * 4];
      const float4 b0 = *(const float4*)&Wt[kk][tx * 4];
      const float ar[8] = {a0.x,a0.y,a0.z,a0.w,a1.x,a1.y,a1.z,a1.w};
      const float bc[4] = {b0.x,b0.y,b0.z,b0.w};
#pragma unroll
      for (int i = 0; i < 8; ++i)
#pragma unroll
        for (int j = 0; j < 4; ++j)
          acc[i][j] += ar[i] * bc[j];
    }
    __syncthreads();
  }
  const int col0 = bn * 64 + tx * 4;
  const float4 Ah4 = *(const float4*)(Avec + col0);
  const float4 bs4 = *(const float4*)(bias + col0);
  const float Ah[4] = {Ah4.x, Ah4.y, Ah4.z, Ah4.w};
  const float bv[4] = {bs4.x, bs4.y, bs4.z, bs4.w};
#pragma unroll
  for (int i = 0; i < 8; ++i) {
    const int gr = bm * 128 + ((i < 4) ? (ty * 4 + i) : (64 + ty * 4 + i - 4));
    const int b = gr >> 11;          // gr = b*2048 + s
    const int s = gr & 2047;
    const int c = s >> 7;            // 128-step chunk
    const float cd = cumd[gr];
    const size_t off = (size_t)gr * 1024 + col0;
    const float4 hin4 = *(const float4*)(chH + (size_t)((b * 16 + c) << 10) + col0);
    const float4 lcl4 = *(const float4*)(C + off);
    const float4 gt4  = *(const float4*)(gate + off);
    const float hin[4] = {hin4.x, hin4.y, hin4.z, hin4.w};
    const float lcl[4] = {lcl4.x, lcl4.y, lcl4.z, lcl4.w};
    const float gt[4]  = {gt4.x, gt4.y, gt4.z, gt4.w};
    float4 o;
    float* po = &o.x;
#pragma unroll
    for (int j = 0; j < 4; ++j) {
      float v = acc[i][j] + bv[j];
      v = 0.5f * v * (1.f + erff(v * 0.70710678118654752f));   // exact gelu
      const float p = __expf(Ah[j] * cd);                      // prod of A_bar over chunk prefix
      const float sst = lcl[j] + p * hin[j];                   // true ssm state
      po[j] = v * gt[j] + sst * (1.f - gt[j]);
    }
    *(float4*)(C + off) = o;
  }
}

// ---------------- reservoir scan: persistent 64-WG kernel, fence-free flag handshake ----------------
// Cross-WG h traffic via LLC-coherent relaxed AGENT atomics (sc-bit ops, no cache maintenance).
// flags[w]=s+1 certifies WG w finished reading h^s AND committed its h^{s+1} slice to LLC.
// Double-buffered hbuf + monotone flags => no overwrite race.
__global__ __launch_bounds__(256, 1) void reservoir_scan_kernel(
    float* __restrict__ xin_res,       // [8][2048][1024]: in xin, out res states (in-place)
    const float* __restrict__ Wres,    // [1024][1024]
    float* __restrict__ hbuf,          // [2][8][1024], zeroed before launch
    unsigned* __restrict__ flags)      // [64], zeroed before launch
{
  const int tid = threadIdx.x;
  const int wg  = blockIdx.x;          // 0..63
  const int g   = tid >> 6;            // wave 0..3
  const int ks  = tid & 63;
  const int j0  = wg * 16;
  __shared__ float hs[8192];           // [8][1024]; aliased as reduction scratch after compute
  float4* hs4 = (float4*)hs;
  unsigned long long* hs8 = (unsigned long long*)hs;

  // W_res slice in registers: rows j0+g*4+r, f4 chunks ks+64*i
  float4 wreg[4][4];
#pragma unroll
  for (int r = 0; r < 4; ++r) {
    const float4* wrow = (const float4*)(Wres + (size_t)(j0 + g * 4 + r) * H_);
#pragma unroll
    for (int i = 0; i < 4; ++i) wreg[r][i] = wrow[ks + 64 * i];
  }

  const int o    = ks & 31;
  const int ob   = o & 7;              // batch
  const int orow = o >> 3;             // 0..3
  const int oj   = j0 + g * 4 + orow;  // global hidden index

  for (int s = 0; s < S_; ++s) {
    // ---- wait until all WGs have posted h^s (wave 0 polls, lane i <-> flag i) ----
    if (tid < 64) {
      for (;;) {
        const unsigned f = __hip_atomic_load(flags + tid, __ATOMIC_RELAXED,
                                             __HIP_MEMORY_SCOPE_AGENT);
        if (__all((int)(f >= (unsigned)s))) break;
        __builtin_amdgcn_s_sleep(1);
      }
    }
    __syncthreads();

    // ---- stage ALL of h^s (8192 floats = 4096 ULL = 16 per thread) via LLC-coherent loads ----
    const unsigned long long* hp =
        (const unsigned long long*)(hbuf + (size_t)(s & 1) * 8192);
#pragma unroll
    for (int half = 0; half < 2; ++half) {
      unsigned long long hld[8];
#pragma unroll
      for (int i = 0; i < 8; ++i)
        hld[i] = __hip_atomic_load(hp + tid + 256 * (half * 8 + i), __ATOMIC_RELAXED,
                                   __HIP_MEMORY_SCOPE_AGENT);
#pragma unroll
      for (int i = 0; i < 8; ++i) hs8[tid + 256 * (half * 8 + i)] = hld[i];
    }
    __syncthreads();

    float acc[4][8];
#pragma unroll
    for (int r = 0; r < 4; ++r)
#pragma unroll
      for (int b = 0; b < 8; ++b) acc[r][b] = 0.f;
#pragma unroll
    for (int i = 0; i < 4; ++i) {
      float4 h4[8];
#pragma unroll
      for (int b = 0; b < 8; ++b) h4[b] = hs4[b * 256 + ks + 64 * i];
#pragma unroll
      for (int r = 0; r < 4; ++r) {
        const float4 w = wreg[r][i];
#pragma unroll
        for (int b = 0; b < 8; ++b) {
          const float4 h = h4[b];
          acc[r][b] += w.x * h.x + w.y * h.y + w.z * h.z + w.w * h.w;
        }
      }
    }
    const float hprev = hs[ob * 1024 + oj];                       // before scratch overwrites
    const float u = xin_res[((size_t)ob * S_ + s) * H_ + oj];     // normal (L2-cached) load
    __syncthreads();                                              // all LDS reads done

    // swizzled per-wave reduction scratch (aliases hs)
    float* red = hs + (g << 11);
#pragma unroll
    for (int r = 0; r < 4; ++r)
#pragma unroll
      for (int b = 0; b < 8; ++b) {
        const int v = r * 8 + b;
        red[ks * 32 + ((v + ks) & 31)] = acc[r][b];
      }
    __syncthreads();
    float psum = 0.f;
    const int half = ks >> 5;
#pragma unroll
    for (int t = 0; t < 32; ++t) {
      const int l = half * 32 + t;
      psum += red[l * 32 + ((o + l) & 31)];
    }
    psum += __shfl_xor(psum, 32);

    const float hn = tanhf(u + psum);
    const float hv = 0.95f * hn + 0.05f * hprev;
    if (ks < 32) {
      xin_res[((size_t)ob * S_ + s) * H_ + oj] = hv;               // normal cached store
      __hip_atomic_store(hbuf + (size_t)((s + 1) & 1) * 8192 + ob * 1024 + oj, hv,
                         __ATOMIC_RELAXED, __HIP_MEMORY_SCOPE_AGENT);
    }
    // drain this wave's vmem (slice stores reach the LLC), then WG-wide rendezvous
    asm volatile("s_waitcnt vmcnt(0)" ::: "memory");
    __syncthreads();
    if (tid == 0)
      __hip_atomic_store(flags + wg, (unsigned)(s + 1), __ATOMIC_RELAXED,
                         __HIP_MEMORY_SCOPE_AGENT);
  }
}

// ---------------- SSM chunked scan ----------------
// within-chunk cumulative delta (tiny)
__global__ __launch_bounds__(128) void cumd_kernel(
    const float* __restrict__ delta, float* __restrict__ cumd)
{
  const int t = threadIdx.x;          // 128 = 8 batches * 16 chunks
  const int b = t >> 4, c = t & 15;
  const int base = b * S_ + c * 128;
  float acc = 0.f;
  for (int i = 0; i < 128; ++i) { acc += delta[base + i]; cumd[base + i] = acc; }
}

// phase A: per-chunk local scan, in-place Bx -> local states; store chunk products
__global__ __launch_bounds__(256) void ssm_partial_kernel(
    const float* __restrict__ delta, const float* __restrict__ Avec,
    float* __restrict__ bx, float* __restrict__ P)
{
  const int idx = blockIdx.x * 256 + threadIdx.x;
  const int h = idx & 1023;
  const int c = (idx >> 10) & 15;
  const int b = idx >> 14;
  const float Ah = Avec[h];
  const float inv = 1.f / (Ah + 1e-8f);
  const float* dp = delta + b * S_ + c * 128;
  float* xp = bx + ((size_t)(b * S_ + c * 128)) * H_ + h;
  float p = 1.f, hl = 0.f;
  for (int t = 0; t < 128; ++t) {
    const float a = __expf(Ah * dp[t]);
    const float bb = xp[(size_t)t * H_] * (1.f - a) * inv;
    hl = a * hl + bb;
    p *= a;
    xp[(size_t)t * H_] = hl;
  }
  P[(b * 16 + c) * 1024 + h] = p;
}

// phase B: sequential combine over 16 chunks -> per-chunk initial states
__global__ __launch_bounds__(256) void ssm_combine_kernel(
    const float* __restrict__ P, const float* __restrict__ local, float* __restrict__ Hin)
{
  const int idx = blockIdx.x * 256 + threadIdx.x;  // 8192
  const int h = idx & 1023;
  const int b = idx >> 10;
  float hh = 0.f;
#pragma unroll
  for (int c = 0; c < 16; ++c) {
    const int o = (b * 16 + c) * 1024 + h;
    Hin[o] = hh;
    hh = P[o] * hh + local[((size_t)(b * S_ + c * 128 + 127)) * H_ + h];
  }
}

// ---------------- host launch ----------------
extern "C" void kernel_launch(void* const* d_in, const int* in_sizes, int n_in,
                              void* d_out, int out_size, void* d_ws, size_t ws_size,
                              hipStream_t stream) {
  (void)in_sizes; (void)n_in; (void)out_size; (void)ws_size;
  const float* x      = (const float*)d_in[0];
  const float* W_in   = (const float*)d_in[1];
  const float* W_res  = (const float*)d_in[2];
  const float* norm_g = (const float*)d_in[3];
  const float* norm_b = (const float*)d_in[4];
  const float* dw     = (const float*)d_in[5];
  const float* db     = (const float*)d_in[6];
  const float* Avec   = (const float*)d_in[7];
  const float* B_w    = (const float*)d_in[8];
  const float* ro_g   = (const float*)d_in[9];
  const float* ro_b   = (const float*)d_in[10];
  const float* ro_w   = (const float*)d_in[11];
  const float* ro_bias= (const float*)d_in[12];
  const float* gate_w = (const float*)d_in[13];
  const float* gate_b = (const float*)d_in[14];
  float* out = (float*)d_out;
  float* ws  = (float*)d_ws;

  float*    buf0   = ws;                    // x_norm, later gate
  float*    buf1   = ws + 16777216;         // xin -> reservoir states (in-place)
  float*    delta  = ws + 33554432;         // [M]
  float*    cumd   = ws + 33570816;         // [M]
  float*    hbuf   = ws + 33587200;         // [2][8][1024]
  unsigned* flags  = (unsigned*)(ws + 33603584);  // [64]
  float2*   stats  = (float2*)(ws + 33603712);
  float*    chP    = ws + 33636480;         // [B,16,1024]
  float*    chH    = ws + 33767552;         // [B,16,1024]

  // 1. layernorm + delta
  ln_delta_kernel<<<M_, 256, 0, stream>>>(x, norm_g, norm_b, dw, db, buf0, delta);
  // 2. xin = x_norm @ W_in^T   -> buf1   (bf16 MFMA)
  gemm_bf16_nt<0><<<1024, 256, 0, stream>>>(buf0, W_in, nullptr, buf1);
  // 3. Bx = x_norm @ B_w^T     -> d_out (scratch)   (bf16 MFMA)
  gemm_bf16_nt<0><<<1024, 256, 0, stream>>>(buf0, B_w, nullptr, out);
  // 4. gate = sigmoid(x @ gate_w^T + gate_b) -> buf0 (x_norm dead)   (bf16 MFMA)
  gemm_bf16_nt<1><<<1024, 256, 0, stream>>>(x, gate_w, gate_b, buf0);
  // 5. ssm chunked scan pieces (independent of reservoir)
  cumd_kernel<<<1, 128, 0, stream>>>(delta, cumd);
  ssm_partial_kernel<<<512, 256, 0, stream>>>(delta, Avec, out, chP);
  ssm_combine_kernel<<<32, 256, 0, stream>>>(chP, out, chH);
  // 6. reservoir scan (zero h0 buffers + flags first; contiguous region)
  hipMemsetAsync(hbuf, 0, (16384 + 64) * sizeof(float), stream);
  reservoir_scan_kernel<<<64, 256, 0, stream>>>(buf1, W_res, hbuf, flags);
  // 7. ro-layernorm stats
  rowstats_kernel<<<M_, 256, 0, stream>>>(buf1, stats);
  // 8. readout GEMM + gelu + ssm reconstruction + gate blend -> d_out
  gemm_readout_kernel<<<2048, 256, 0, stream>>>(buf1, ro_w, ro_bias, stats, ro_g, ro_b,
                                                Avec, cumd, chH, buf0, out);
}

// Round 4
// 9996.987 us; speedup vs baseline: 1.9471x; 1.3097x over previous
//
#include <hip/hip_runtime.h>
#include <math.h>

#define B_ 8
#define S_ 2048
#define E_ 1024
#define H_ 1024
#define M_ 16384   // B_*S_

typedef __attribute__((ext_vector_type(8))) short short8;    // 8 bf16 = 4 VGPRs
typedef __attribute__((ext_vector_type(4))) float floatx4;

// ---------------- block-wide reduction of two floats (256 threads = 4 waves) ----------------
__device__ __forceinline__ void block_reduce2(float &a, float &b) {
#pragma unroll
  for (int off = 32; off > 0; off >>= 1) {
    a += __shfl_down(a, off);
    b += __shfl_down(b, off);
  }
  __shared__ float sa[4], sb[4];
  const int w = threadIdx.x >> 6;
  __syncthreads();                 // protects reuse across back-to-back calls
  if ((threadIdx.x & 63) == 0) { sa[w] = a; sb[w] = b; }
  __syncthreads();
  a = sa[0] + sa[1] + sa[2] + sa[3];
  b = sb[0] + sb[1] + sb[2] + sb[3];
}

// ---------------- LayerNorm(x) -> x_norm, plus delta = softplus(x_norm . delta_w + delta_b) ----------------
__global__ __launch_bounds__(256) void ln_delta_kernel(
    const float* __restrict__ x, const float* __restrict__ g, const float* __restrict__ bt,
    const float* __restrict__ dw, const float* __restrict__ db,
    float* __restrict__ xn, float* __restrict__ delta)
{
  const int row = blockIdx.x;
  const int t = threadIdx.x;
  const float4 v = ((const float4*)(x + (size_t)row * E_))[t];
  float s1 = v.x + v.y + v.z + v.w;
  float s2 = v.x*v.x + v.y*v.y + v.z*v.z + v.w*v.w;
  block_reduce2(s1, s2);
  const float mean = s1 * (1.f / E_);
  const float var  = s2 * (1.f / E_) - mean * mean;
  const float rstd = rsqrtf(var + 1e-5f);
  const float4 g4 = ((const float4*)g)[t];
  const float4 b4 = ((const float4*)bt)[t];
  float4 o;
  o.x = (v.x - mean) * rstd * g4.x + b4.x;
  o.y = (v.y - mean) * rstd * g4.y + b4.y;
  o.z = (v.z - mean) * rstd * g4.z + b4.z;
  o.w = (v.w - mean) * rstd * g4.w + b4.w;
  ((float4*)(xn + (size_t)row * E_))[t] = o;
  const float4 d4 = ((const float4*)dw)[t];
  float dd = o.x*d4.x + o.y*d4.y + o.z*d4.z + o.w*d4.w;
  float dummy = 0.f;
  block_reduce2(dd, dummy);
  if (t == 0) {
    const float z = dd + db[0];
    delta[row] = (z > 20.f) ? z : log1pf(__expf(z));
  }
}

// ---------------- per-row mean/rstd of reservoir states (for fused ro-layernorm) ----------------
__global__ __launch_bounds__(256) void rowstats_kernel(
    const float* __restrict__ res, float2* __restrict__ st)
{
  const int row = blockIdx.x;
  const int t = threadIdx.x;
  const float4 v = ((const float4*)(res + (size_t)row * H_))[t];
  float s1 = v.x + v.y + v.z + v.w;
  float s2 = v.x*v.x + v.y*v.y + v.z*v.z + v.w*v.w;
  block_reduce2(s1, s2);
  if (t == 0) {
    const float m = s1 * (1.f / H_);
    const float var = s2 * (1.f / H_) - m * m;
    st[row] = make_float2(m, rsqrtf(var + 1e-5f));
  }
}

// ---------------- bf16 MFMA GEMM: C[M,N] = act(A[M,1024] @ W[N,1024]^T + bias) ----------------
__device__ __forceinline__ unsigned pack_bf16(float lo, float hi) {
  return __builtin_amdgcn_perm(__float_as_uint(hi) + 0x8000u,
                               __float_as_uint(lo) + 0x8000u, 0x07060302u);
}

template<int ACT>
__global__ __launch_bounds__(256) void gemm_bf16_nt(
    const float* __restrict__ A, const float* __restrict__ W,
    const float* __restrict__ bias, float* __restrict__ C)
{
  __shared__ __align__(16) unsigned short As[128 * 40];
  __shared__ __align__(16) unsigned short Ws[128 * 40];
  const int tid  = threadIdx.x;
  const int bn   = blockIdx.x & 7;
  const int bm   = blockIdx.x >> 3;
  const int wave = tid >> 6, lane = tid & 63;
  const int wm = (wave >> 1) * 64, wn = (wave & 1) * 64;
  const int fm = lane & 15, quad = lane >> 4;

  floatx4 acc[4][4];
#pragma unroll
  for (int i = 0; i < 4; ++i)
#pragma unroll
    for (int j = 0; j < 4; ++j) acc[i][j] = (floatx4){0.f, 0.f, 0.f, 0.f};

  const float* Abase = A + (size_t)bm * 128 * 1024;
  const float* Wbase = W + (size_t)bn * 128 * 1024;

  for (int k0 = 0; k0 < 1024; k0 += 32) {
    float4 a4[4], w4[4];
#pragma unroll
    for (int i = 0; i < 4; ++i) {
      const int q = tid + 256 * i;
      const int row = q >> 3, ch = q & 7;
      a4[i] = *(const float4*)(Abase + (size_t)row * 1024 + k0 + ch * 4);
      w4[i] = *(const float4*)(Wbase + (size_t)row * 1024 + k0 + ch * 4);
    }
#pragma unroll
    for (int i = 0; i < 4; ++i) {
      const int q = tid + 256 * i;
      const int row = q >> 3, ch = q & 7;
      uint2 pa, pw;
      pa.x = pack_bf16(a4[i].x, a4[i].y); pa.y = pack_bf16(a4[i].z, a4[i].w);
      pw.x = pack_bf16(w4[i].x, w4[i].y); pw.y = pack_bf16(w4[i].z, w4[i].w);
      *(uint2*)(&As[row * 40 + ch * 4]) = pa;
      *(uint2*)(&Ws[row * 40 + ch * 4]) = pw;
    }
    __syncthreads();
    short8 af[4], wf[4];
#pragma unroll
    for (int i = 0; i < 4; ++i) {
      af[i] = *(const short8*)(&As[(wm + i * 16 + fm) * 40 + quad * 8]);
      wf[i] = *(const short8*)(&Ws[(wn + i * 16 + fm) * 40 + quad * 8]);
    }
#pragma unroll
    for (int i = 0; i < 4; ++i)
#pragma unroll
      for (int j = 0; j < 4; ++j)
        acc[i][j] = __builtin_amdgcn_mfma_f32_16x16x32_bf16(af[i], wf[j], acc[i][j], 0, 0, 0);
    __syncthreads();
  }

  // epilogue: C/D layout col=lane&15, row=quad*4+reg (m89/m91)
#pragma unroll
  for (int i = 0; i < 4; ++i) {
    const int grow0 = bm * 128 + wm + i * 16 + quad * 4;
#pragma unroll
    for (int j = 0; j < 4; ++j) {
      const int gcol = bn * 128 + wn + j * 16 + fm;
      const float bb = (ACT == 1) ? bias[gcol] : 0.f;
#pragma unroll
      for (int r = 0; r < 4; ++r) {
        float v = acc[i][j][r] + bb;
        if (ACT == 1) v = 1.f / (1.f + __expf(-v));
        C[(size_t)(grow0 + r) * 1024 + gcol] = v;
      }
    }
  }
}

// ---------------- readout GEMM: fused ro-layernorm on A, gelu, ssm reconstruction, gate blend ----------------
__global__ __launch_bounds__(256) void gemm_readout_kernel(
    const float* __restrict__ A,      // reservoir states [M,1024]
    const float* __restrict__ W,      // ro_w [1024,1024]
    const float* __restrict__ bias,   // ro_bias
    const float2* __restrict__ lnst,  // per-row mean/rstd
    const float* __restrict__ lng, const float* __restrict__ lnb,
    const float* __restrict__ Avec,   // A[h]
    const float* __restrict__ cumd,   // within-chunk cumulative delta [M]
    const float* __restrict__ chH,    // per-chunk initial ssm state [B,16,1024]
    const float* __restrict__ gate,   // [M,1024]
    float* __restrict__ C)            // d_out: in = ssm local states, out = final
{
  __shared__ float As[16][132];
  __shared__ float Wt[16][68];
  const int tid = threadIdx.x;
  const int bn = blockIdx.x & 15;
  const int bm = blockIdx.x >> 4;
  const int tx = tid & 15;
  const int ty = tid >> 4;
  const int sr = tid >> 2;
  const int sk = tid & 3;
  float acc[8][4];
#pragma unroll
  for (int i = 0; i < 8; ++i)
#pragma unroll
    for (int j = 0; j < 4; ++j) acc[i][j] = 0.f;

  for (int k0 = 0; k0 < 1024; k0 += 16) {
    const float4 g4 = *(const float4*)(lng + k0 + sk * 4);
    const float4 b4 = *(const float4*)(lnb + k0 + sk * 4);
#pragma unroll
    for (int p = 0; p < 2; ++p) {
      const int row = sr + p * 64;
      const int gr = bm * 128 + row;
      float4 a4 = *(const float4*)(A + (size_t)gr * 1024 + k0 + sk * 4);
      const float2 st = lnst[gr];
      a4.x = (a4.x - st.x) * st.y * g4.x + b4.x;
      a4.y = (a4.y - st.x) * st.y * g4.y + b4.y;
      a4.z = (a4.z - st.x) * st.y * g4.z + b4.z;
      a4.w = (a4.w - st.x) * st.y * g4.w + b4.w;
      As[sk*4+0][row] = a4.x; As[sk*4+1][row] = a4.y;
      As[sk*4+2][row] = a4.z; As[sk*4+3][row] = a4.w;
    }
    {
      const float4 w4 = *(const float4*)(W + (size_t)(bn * 64 + sr) * 1024 + k0 + sk * 4);
      Wt[sk*4+0][sr] = w4.x; Wt[sk*4+1][sr] = w4.y;
      Wt[sk*4+2][sr] = w4.z; Wt[sk*4+3][sr] = w4.w;
    }
    __syncthreads();
#pragma unroll
    for (int kk = 0; kk < 16; ++kk) {
      const float4 a0 = *(const float4*)&As[kk][ty * 4];
      const float4 a1 = *(const float4*)&As[kk][64 + ty * 4];
      const float4 b0 = *(const float4*)&Wt[kk][tx * 4];
      const float ar[8] = {a0.x,a0.y,a0.z,a0.w,a1.x,a1.y,a1.z,a1.w};
      const float bc[4] = {b0.x,b0.y,b0.z,b0.w};
#pragma unroll
      for (int i = 0; i < 8; ++i)
#pragma unroll
        for (int j = 0; j < 4; ++j)
          acc[i][j] += ar[i] * bc[j];
    }
    __syncthreads();
  }
  const int col0 = bn * 64 + tx * 4;
  const float4 Ah4 = *(const float4*)(Avec + col0);
  const float4 bs4 = *(const float4*)(bias + col0);
  const float Ah[4] = {Ah4.x, Ah4.y, Ah4.z, Ah4.w};
  const float bv[4] = {bs4.x, bs4.y, bs4.z, bs4.w};
#pragma unroll
  for (int i = 0; i < 8; ++i) {
    const int gr = bm * 128 + ((i < 4) ? (ty * 4 + i) : (64 + ty * 4 + i - 4));
    const int b = gr >> 11;          // gr = b*2048 + s
    const int s = gr & 2047;
    const int c = s >> 7;            // 128-step chunk
    const float cd = cumd[gr];
    const size_t off = (size_t)gr * 1024 + col0;
    const float4 hin4 = *(const float4*)(chH + (size_t)((b * 16 + c) << 10) + col0);
    const float4 lcl4 = *(const float4*)(C + off);
    const float4 gt4  = *(const float4*)(gate + off);
    const float hin[4] = {hin4.x, hin4.y, hin4.z, hin4.w};
    const float lcl[4] = {lcl4.x, lcl4.y, lcl4.z, lcl4.w};
    const float gt[4]  = {gt4.x, gt4.y, gt4.z, gt4.w};
    float4 o;
    float* po = &o.x;
#pragma unroll
    for (int j = 0; j < 4; ++j) {
      float v = acc[i][j] + bv[j];
      v = 0.5f * v * (1.f + erff(v * 0.70710678118654752f));   // exact gelu
      const float p = __expf(Ah[j] * cd);                      // prod of A_bar over chunk prefix
      const float sst = lcl[j] + p * hin[j];                   // true ssm state
      po[j] = v * gt[j] + sst * (1.f - gt[j]);
    }
    *(float4*)(C + off) = o;
  }
}

// ---------------- reservoir scan: persistent 64-WG kernel, data-as-flag handshake ----------------
// Each exchanged h-word is self-certifying: (bf16(h) << 16) | step_tag, stored/loaded with
// relaxed AGENT-scope atomics (LLC-coherent, no cache maintenance, no fences). Consumers
// poll their staging loads until all tags == s: ONE LLC round trip per step.
// Safety: a lane stores tag s+1 only after its WG's __syncthreads chain, i.e. after ALL its
// lanes finished reading tag-s words; a WG reaches tag s+2 (overwriting parity buffer s)
// only after observing all tag-s+1 words, which certifies every WG consumed buffer s.
__global__ __launch_bounds__(256, 1) void reservoir_scan_kernel(
    float* __restrict__ xin_res,       // [8][2048][1024]: in xin, out res states (in-place)
    const float* __restrict__ Wres,    // [1024][1024]
    unsigned* __restrict__ hbuf,       // [2][8192] packed words, zeroed before launch (tag 0, h=0)
    unsigned* __restrict__ unused)
{
  const int tid = threadIdx.x;
  const int wg  = blockIdx.x;          // 0..63
  const int g   = tid >> 6;            // wave 0..3
  const int ks  = tid & 63;
  const int j0  = wg * 16;
  __shared__ float hs[8192];           // [8][1024]; aliased as reduction scratch after compute
  float4* hs4 = (float4*)hs;

  // W_res slice in registers: rows j0+g*4+r, f4 chunks ks+64*i
  float4 wreg[4][4];
#pragma unroll
  for (int r = 0; r < 4; ++r) {
    const float4* wrow = (const float4*)(Wres + (size_t)(j0 + g * 4 + r) * H_);
#pragma unroll
    for (int i = 0; i < 4; ++i) wreg[r][i] = wrow[ks + 64 * i];
  }

  const int o    = ks & 31;
  const int ob   = o & 7;              // batch
  const int orow = o >> 3;             // 0..3
  const int oj   = j0 + g * 4 + orow;  // global hidden index

  for (int s = 0; s < S_; ++s) {
    // ---- poll+load h^s: staging loads ARE the sync (tag == s certifies payload) ----
    const unsigned tag = (unsigned)s & 0xFFFFu;
    const unsigned* hp = hbuf + (size_t)(s & 1) * 8192;
    unsigned w[32];
    for (;;) {
      bool ok = true;
#pragma unroll
      for (int i = 0; i < 32; ++i)
        w[i] = __hip_atomic_load(hp + tid + 256 * i, __ATOMIC_RELAXED,
                                 __HIP_MEMORY_SCOPE_AGENT);
#pragma unroll
      for (int i = 0; i < 32; ++i) ok &= ((w[i] & 0xFFFFu) == tag);
      if (ok) break;
      __builtin_amdgcn_s_sleep(1);
    }
    __syncthreads();                   // prev-step reduction reads of hs complete everywhere
#pragma unroll
    for (int i = 0; i < 32; ++i)
      hs[tid + 256 * i] = __uint_as_float(w[i] & 0xFFFF0000u);
    __syncthreads();                   // h^s fully staged (also: all lanes' polls done
                                       // BEFORE any lane's tag-s+1 store below — safety inv.)

    float acc[4][8];
#pragma unroll
    for (int r = 0; r < 4; ++r)
#pragma unroll
      for (int b = 0; b < 8; ++b) acc[r][b] = 0.f;
#pragma unroll
    for (int i = 0; i < 4; ++i) {
      float4 h4[8];
#pragma unroll
      for (int b = 0; b < 8; ++b) h4[b] = hs4[b * 256 + ks + 64 * i];
#pragma unroll
      for (int r = 0; r < 4; ++r) {
        const float4 ww = wreg[r][i];
#pragma unroll
        for (int b = 0; b < 8; ++b) {
          const float4 h = h4[b];
          acc[r][b] += ww.x * h.x + ww.y * h.y + ww.z * h.z + ww.w * h.w;
        }
      }
    }
    const float hprev = hs[ob * 1024 + oj];                       // before scratch overwrites
    const float u = xin_res[((size_t)ob * S_ + s) * H_ + oj];     // normal (L2-cached) load
    __syncthreads();                                              // all LDS reads done

    // swizzled per-wave reduction scratch (aliases hs)
    float* red = hs + (g << 11);
#pragma unroll
    for (int r = 0; r < 4; ++r)
#pragma unroll
      for (int b = 0; b < 8; ++b) {
        const int v = r * 8 + b;
        red[ks * 32 + ((v + ks) & 31)] = acc[r][b];
      }
    __syncthreads();
    float psum = 0.f;
    const int half = ks >> 5;
#pragma unroll
    for (int t = 0; t < 32; ++t) {
      const int l = half * 32 + t;
      psum += red[l * 32 + ((o + l) & 31)];
    }
    psum += __shfl_xor(psum, 32);

    const float hn = tanhf(u + psum);
    const float hv = 0.95f * hn + 0.05f * hprev;
    if (ks < 32) {
      xin_res[((size_t)ob * S_ + s) * H_ + oj] = hv;               // full fp32 to readout path
      const unsigned word = ((__float_as_uint(hv) + 0x8000u) & 0xFFFF0000u)
                          | ((unsigned)(s + 1) & 0xFFFFu);
      __hip_atomic_store(hbuf + (size_t)((s + 1) & 1) * 8192 + ob * 1024 + oj, word,
                         __ATOMIC_RELAXED, __HIP_MEMORY_SCOPE_AGENT);
    }
    // no drain, no flag, no rendezvous — next iteration's poll is the wait
  }
}

// ---------------- SSM chunked scan ----------------
// within-chunk cumulative delta (tiny)
__global__ __launch_bounds__(128) void cumd_kernel(
    const float* __restrict__ delta, float* __restrict__ cumd)
{
  const int t = threadIdx.x;          // 128 = 8 batches * 16 chunks
  const int b = t >> 4, c = t & 15;
  const int base = b * S_ + c * 128;
  float acc = 0.f;
  for (int i = 0; i < 128; ++i) { acc += delta[base + i]; cumd[base + i] = acc; }
}

// phase A: per-chunk local scan, in-place Bx -> local states; store chunk products
__global__ __launch_bounds__(256) void ssm_partial_kernel(
    const float* __restrict__ delta, const float* __restrict__ Avec,
    float* __restrict__ bx, float* __restrict__ P)
{
  const int idx = blockIdx.x * 256 + threadIdx.x;
  const int h = idx & 1023;
  const int c = (idx >> 10) & 15;
  const int b = idx >> 14;
  const float Ah = Avec[h];
  const float inv = 1.f / (Ah + 1e-8f);
  const float* dp = delta + b * S_ + c * 128;
  float* xp = bx + ((size_t)(b * S_ + c * 128)) * H_ + h;
  float p = 1.f, hl = 0.f;
  for (int t = 0; t < 128; ++t) {
    const float a = __expf(Ah * dp[t]);
    const float bb = xp[(size_t)t * H_] * (1.f - a) * inv;
    hl = a * hl + bb;
    p *= a;
    xp[(size_t)t * H_] = hl;
  }
  P[(b * 16 + c) * 1024 + h] = p;
}

// phase B: sequential combine over 16 chunks -> per-chunk initial states
__global__ __launch_bounds__(256) void ssm_combine_kernel(
    const float* __restrict__ P, const float* __restrict__ local, float* __restrict__ Hin)
{
  const int idx = blockIdx.x * 256 + threadIdx.x;  // 8192
  const int h = idx & 1023;
  const int b = idx >> 10;
  float hh = 0.f;
#pragma unroll
  for (int c = 0; c < 16; ++c) {
    const int o = (b * 16 + c) * 1024 + h;
    Hin[o] = hh;
    hh = P[o] * hh + local[((size_t)(b * S_ + c * 128 + 127)) * H_ + h];
  }
}

// ---------------- host launch ----------------
extern "C" void kernel_launch(void* const* d_in, const int* in_sizes, int n_in,
                              void* d_out, int out_size, void* d_ws, size_t ws_size,
                              hipStream_t stream) {
  (void)in_sizes; (void)n_in; (void)out_size; (void)ws_size;
  const float* x      = (const float*)d_in[0];
  const float* W_in   = (const float*)d_in[1];
  const float* W_res  = (const float*)d_in[2];
  const float* norm_g = (const float*)d_in[3];
  const float* norm_b = (const float*)d_in[4];
  const float* dw     = (const float*)d_in[5];
  const float* db     = (const float*)d_in[6];
  const float* Avec   = (const float*)d_in[7];
  const float* B_w    = (const float*)d_in[8];
  const float* ro_g   = (const float*)d_in[9];
  const float* ro_b   = (const float*)d_in[10];
  const float* ro_w   = (const float*)d_in[11];
  const float* ro_bias= (const float*)d_in[12];
  const float* gate_w = (const float*)d_in[13];
  const float* gate_b = (const float*)d_in[14];
  float* out = (float*)d_out;
  float* ws  = (float*)d_ws;

  float*    buf0   = ws;                    // x_norm, later gate
  float*    buf1   = ws + 16777216;         // xin -> reservoir states (in-place)
  float*    delta  = ws + 33554432;         // [M]
  float*    cumd   = ws + 33570816;         // [M]
  unsigned* hbuf   = (unsigned*)(ws + 33587200);  // [2][8192] packed words
  float2*   stats  = (float2*)(ws + 33603712);
  float*    chP    = ws + 33636480;         // [B,16,1024]
  float*    chH    = ws + 33767552;         // [B,16,1024]

  // 1. layernorm + delta
  ln_delta_kernel<<<M_, 256, 0, stream>>>(x, norm_g, norm_b, dw, db, buf0, delta);
  // 2. xin = x_norm @ W_in^T   -> buf1   (bf16 MFMA)
  gemm_bf16_nt<0><<<1024, 256, 0, stream>>>(buf0, W_in, nullptr, buf1);
  // 3. Bx = x_norm @ B_w^T     -> d_out (scratch)   (bf16 MFMA)
  gemm_bf16_nt<0><<<1024, 256, 0, stream>>>(buf0, B_w, nullptr, out);
  // 4. gate = sigmoid(x @ gate_w^T + gate_b) -> buf0 (x_norm dead)   (bf16 MFMA)
  gemm_bf16_nt<1><<<1024, 256, 0, stream>>>(x, gate_w, gate_b, buf0);
  // 5. ssm chunked scan pieces (independent of reservoir)
  cumd_kernel<<<1, 128, 0, stream>>>(delta, cumd);
  ssm_partial_kernel<<<512, 256, 0, stream>>>(delta, Avec, out, chP);
  ssm_combine_kernel<<<32, 256, 0, stream>>>(chP, out, chH);
  // 6. reservoir scan (zero both parity buffers: word 0 == tag 0 | bf16(0))
  hipMemsetAsync(hbuf, 0, 2 * 8192 * sizeof(unsigned), stream);
  reservoir_scan_kernel<<<64, 256, 0, stream>>>(buf1, W_res, hbuf, nullptr);
  // 7. ro-layernorm stats
  rowstats_kernel<<<M_, 256, 0, stream>>>(buf1, stats);
  // 8. readout GEMM + gelu + ssm reconstruction + gate blend -> d_out
  gemm_readout_kernel<<<2048, 256, 0, stream>>>(buf1, ro_w, ro_bias, stats, ro_g, ro_b,
                                                Avec, cumd, chH, buf0, out);
}